// Round 20
// baseline (36.012 us; speedup 1.0000x reference)
//
#include <hip/hip_runtime.h>

// EctLayer: ect[b,r,t] = sum_{n: batch[n]==b} sigmoid(SCALE*(lin[r] - (x[n]·dir[:,t])))
// N=65536, D=3, T=64, R=64, B=64. SCALE=500.
//
// Round-20: r19 base + ONE change: speculative L2-warm of x concurrent with
// the boundary scan. Harness poison-fills (268MB) flush L2/L3 between timed
// replays, so scan->x first-touches are SERIAL HBM exposures (~900cyc each).
// The block's x-range is known statistically before the scan resolves
// (lo in b*1024 +- 768): issue 5 clamped float4 touch-loads/thread covering
// points [b*1024-1024, b*1024+2389) in the same issue burst as the scan
// loads; keep live via accumulate + asm-consume (no DCE). Critical path:
// {scan || warm} + L2-hit x loads, instead of {scan -> cold x}.
//  - inner mapping (r19): lane = point, 64 consecutive points/wave-iter,
//    4 dirs/lane in registers; packed ds_add_u32 (1<<20)|si at bin
//    j1=clamp(r0+1,0,64), si=round(sigmoid*2^9); skip r0>=64.
//  - single-exposure boundary scan (+-1024), analytic lo(0)=0 / hi(63)=N,
//    full-sweep fallback iff sentinel survives (prob ~1e-15).
//  - epilogue: wave 0 only; uint4 bins, 6-step __shfl_up scan, float4 store.
//  - 1024 blocks = (b = bid>>4, q = bid&15) x 512 threads; disjoint
//    out[b,:,q*4..+4) slices; no global atomics, no memset, no pre/post
//    kernels; 3 hot-path syncs.
//  - errors: quant ~0.06, dropped tails <= ~0.2; threshold 19.44.

#define T_DIRS   64
#define R_STEPS  64
#define NROWS    65                     // bins 0..64
#define N_BATCH  64
#define TSPLIT   16
#define TQW      4                      // dirs per block
#define THREADS  512
#define NWAVES   8

#define RADIUS_F 1.1f
#define STEP_F   (2.0f * RADIUS_F / (R_STEPS - 1))          // 0.0349206
#define INV_STEP (1.0f / STEP_F)
#define OFF_F    (RADIUS_F * INV_STEP)                      // 31.5
#define MEXP     (-500.0f * STEP_F * 1.4426950408889634f)   // -K*log2(e)
#define FIXP     512.0f
#define INV_FIXP (1.0f / 512.0f)
#define CNT_ONE  (1u << 20)
#define SI_MASK  0xFFFFFu

__global__ __launch_bounds__(THREADS) void ect_kernel(
    const float* __restrict__ x,      // [N,3]
    const float* __restrict__ dirs,   // [3,T]
    const int*   __restrict__ batch,  // [N] sorted, values in [0,64)
    float* __restrict__ out,          // [B,R,T]
    int N)
{
    __shared__ unsigned s_a[NROWS * TQW];       // 1040 B packed bins
    __shared__ int      s_lo, s_hi;

    const int tid  = threadIdx.x;
    const int b    = blockIdx.x >> 4;
    const int q    = blockIdx.x & (TSPLIT - 1);
    const int lane = tid & 63;
    const int w    = tid >> 6;

    const int seg = N >> 6;                     // 1024
    const int clo = b * seg;
    const int chi = (b + 1) * seg;
    const bool doLo = (b != 0);
    const bool doHi = (b != N_BATCH - 1);       // uniform branches
    const int lob = clo - 1024 + 4 * tid;       // 16B-aligned
    const int hib = chi - 1024 + 4 * tid;

    // ---- issue burst 1: scan loads ----
    int4 elo, ehi;
    int  plo = -1, phi = -1;
    if (doLo) {
        elo = *(const int4*)&batch[lob];
        plo = (lob == 0) ? -1 : batch[lob - 1];
    }
    if (doHi) {
        ehi = *(const int4*)&batch[hib];
        phi = (hib == 0) ? -1 : batch[hib - 1];
    }

    // ---- issue burst 2 (same exposure): speculative x warm ----
    // floats [3*(clo-1024) + 20*tid, +20) clamped to [0, 3N-4]
    float warmacc;
    {
        const int fmax = 3 * N - 4;
        int f0 = 3 * clo - 3072 + 20 * tid;
        float4 t0 = *(const float4*)&x[min(max(f0,      0), fmax)];
        float4 t1 = *(const float4*)&x[min(max(f0 + 4,  0), fmax)];
        float4 t2 = *(const float4*)&x[min(max(f0 + 8,  0), fmax)];
        float4 t3 = *(const float4*)&x[min(max(f0 + 12, 0), fmax)];
        float4 t4 = *(const float4*)&x[min(max(f0 + 16, 0), fmax)];
        warmacc = t0.x + t0.y + t0.z + t0.w + t1.x + t1.y + t1.z + t1.w
                + t2.x + t2.y + t2.z + t2.w + t3.x + t3.y + t3.z + t3.w
                + t4.x + t4.y + t4.z + t4.w;
    }

    // LDS init + dirs while loads fly
    for (int i = tid; i < NROWS * TQW; i += THREADS) s_a[i] = 0u;
    if (tid == 0) {
        s_lo = (b == 0) ? 0 : -1;               // analytic: batch[j] >= 0
        s_hi = (b == N_BATCH - 1) ? N : -1;     // analytic: batch[j] <= 63
    }
    float D0[TQW], D1[TQW], D2[TQW];
#pragma unroll
    for (int j = 0; j < TQW; ++j) {
        D0[j] = dirs[q * TQW + j];
        D1[j] = dirs[T_DIRS + q * TQW + j];
        D2[j] = dirs[2 * T_DIRS + q * TQW + j];
    }

    // scan compares (single-writer)
    if (doLo) {
        int v[5] = {plo, elo.x, elo.y, elo.z, elo.w};
#pragma unroll
        for (int i = 0; i < 4; ++i)
            if (v[i + 1] >= b && v[i] < b) s_lo = lob + i;
    }
    if (doHi) {
        int v[5] = {phi, ehi.x, ehi.y, ehi.z, ehi.w};
#pragma unroll
        for (int i = 0; i < 4; ++i)
            if (v[i + 1] > b && v[i] <= b) s_hi = hib + i;
    }
    asm volatile("" :: "v"(warmacc));           // keep warm loads live (no DCE)
    __syncthreads();

    // fallback: full coalesced sweep iff a sentinel survived (prob ~1e-15)
    if (s_lo < 0 || s_hi < 0) {
        for (int j = tid; j < N; j += THREADS) {
            int v  = batch[j];
            int vp = (j == 0) ? -1 : batch[j - 1];
            if (v >= b && vp < b)  s_lo = j;
            if (v >  b && vp <= b) s_hi = j;
        }
        __syncthreads();
    }
    const int lo  = (s_lo < 0) ? N : s_lo;
    const int hi  = (s_hi < 0) ? N : s_hi;
    const int len = hi - lo;
    const float* xb = x + (size_t)lo * 3;

    // inner loop: lane = point; 64 consecutive points/wave-iter (L2-warm);
    // 4 dirs per lane in registers; ~2 serial iterations for len~1024.
    for (int p0 = w * 64; p0 < len; p0 += NWAVES * 64) {
        int p = p0 + lane;
        if (p < len) {
            float x0 = xb[p * 3 + 0];
            float x1 = xb[p * 3 + 1];
            float x2 = xb[p * 3 + 2];
#pragma unroll
            for (int j = 0; j < TQW; ++j) {
                float nh  = fmaf(x2, D2[j], fmaf(x1, D1[j], x0 * D0[j]));
                float u   = fmaf(nh, INV_STEP, OFF_F);
                float r0f = rintf(u);
                float dd  = r0f - u;                           // [-0.5, 0.5]
                float e   = __builtin_amdgcn_exp2f(dd * MEXP);
                float s   = __builtin_amdgcn_rcpf(1.0f + e);   // sigmoid at r0
                unsigned si = (unsigned)fmaf(s, FIXP, 0.5f);   // [0, 2^9]
                int j1 = (int)r0f + 1;
                if (j1 <= R_STEPS) {            // skip upper-tail trash
                    j1 = max(j1, 0);
                    atomicAdd(&s_a[j1 * TQW + j], CNT_ONE | si);
                }
            }
        }
    }
    __syncthreads();
    if (w != 0) return;                         // single-wave epilogue

    // lane r handles output row r for the block's 4 dirs.
    uint4 rowv = *(const uint4*)&s_a[lane * TQW];          // ds_read_b128
    uint4 r64  = *(const uint4*)&s_a[R_STEPS * TQW];       // row 64 broadcast

    unsigned c0 = rowv.x >> 20, c1 = rowv.y >> 20,
             c2 = rowv.z >> 20, c3 = rowv.w >> 20;
    unsigned s0 = rowv.x & SI_MASK, s1 = rowv.y & SI_MASK,
             s2 = rowv.z & SI_MASK, s3 = rowv.w & SI_MASK;

    unsigned n0 = __shfl_down(s0, 1, 64), n1 = __shfl_down(s1, 1, 64),
             n2 = __shfl_down(s2, 1, 64), n3 = __shfl_down(s3, 1, 64);
    if (lane == 63) {
        n0 = r64.x & SI_MASK; n1 = r64.y & SI_MASK;
        n2 = r64.z & SI_MASK; n3 = r64.w & SI_MASK;
    }

#pragma unroll
    for (int d = 1; d < 64; d <<= 1) {
        unsigned u0 = __shfl_up(c0, d, 64), u1 = __shfl_up(c1, d, 64),
                 u2 = __shfl_up(c2, d, 64), u3 = __shfl_up(c3, d, 64);
        if (lane >= d) { c0 += u0; c1 += u1; c2 += u2; c3 += u3; }
    }

    float4 o;
    o.x = (float)c0 + (float)n0 * INV_FIXP;
    o.y = (float)c1 + (float)n1 * INV_FIXP;
    o.z = (float)c2 + (float)n2 * INV_FIXP;
    o.w = (float)c3 + (float)n3 * INV_FIXP;
    *(float4*)&out[((size_t)b << 12) | (lane << 6) | (q * TQW)] = o;
}

extern "C" void kernel_launch(void* const* d_in, const int* in_sizes, int n_in,
                              void* d_out, int out_size, void* d_ws, size_t ws_size,
                              hipStream_t stream) {
    const float* x     = (const float*)d_in[0];
    const float* dirs  = (const float*)d_in[1];
    const int*   batch = (const int*)d_in[3];
    float* out = (float*)d_out;
    const int N = in_sizes[3];

    ect_kernel<<<dim3(N_BATCH * TSPLIT), dim3(THREADS), 0, stream>>>(
        x, dirs, batch, out, N);
}

// Round 21
// 11.714 us; speedup vs baseline: 3.0744x; 3.0744x over previous
//
#include <hip/hip_runtime.h>

// EctLayer: ect[b,r,t] = sum_{n: batch[n]==b} sigmoid(SCALE*(lin[r] - (x[n]·dir[:,t])))
// N=65536, D=3, T=64, R=64, B=64. SCALE=500.
//
// Round-21: EXACT revert to r19 (best: 11.71us). r20's speculative x-warm
// regressed 3x (forced vmcnt(0) on 11 outstanding loads + 40KB/block of
// redundant speculative fetch flooding cold L2). Final structure:
//  - 1024 blocks = (batch b = bid>>4, t-16th q = bid&15) x 512 threads;
//    block writes disjoint out[b,:,q*4..+4) slice, plain float4 stores;
//    no global atomics, no memset, no pre/post kernels; 3 hot-path syncs.
//  - single-exposure boundary scan: window +-1024 around b*1024 (8 sigma of
//    cumulative binomial), one aligned int4 + guard scalar per window, all
//    loads issued back-to-back (1 latency exposure); single-writer stores;
//    analytic lo(0)=0 / hi(63)=N; full-sweep fallback iff a sentinel
//    survives (prob ~1e-15).
//  - inner loop: lane = point (64 consecutive points/wave-iter, coalesced
//    3x256B loads, ~2 serial exposures); 4 dirs/lane in registers (12
//    block-uniform scalars); saturation histogram: u=(nh+R)/step,
//    r0=rint(u), s=sigmoid at r0 via exp2+rcp, si=round(s*2^9); ONE packed
//    ds_add_u32 (1<<20)|si at bin j1=clamp(r0+1,0,64), skip r0>=64.
//    count=high 12 bits, si-sum=low 20 (len<2048 -> no overflow).
//  - epilogue: wave 0 only; uint4 bins read, 6-step __shfl_up inclusive
//    scan (4 dirs in parallel), float4 store:
//    out[r] = countPrefix(0..r) + (bin[r+1]&0xFFFFF)*2^-9.
//  - errors: quant ~0.06, dropped tails <= ~0.2; threshold 19.44.

#define T_DIRS   64
#define R_STEPS  64
#define NROWS    65                     // bins 0..64
#define N_BATCH  64
#define TSPLIT   16
#define TQW      4                      // dirs per block
#define THREADS  512
#define NWAVES   8

#define RADIUS_F 1.1f
#define STEP_F   (2.0f * RADIUS_F / (R_STEPS - 1))          // 0.0349206
#define INV_STEP (1.0f / STEP_F)
#define OFF_F    (RADIUS_F * INV_STEP)                      // 31.5
#define MEXP     (-500.0f * STEP_F * 1.4426950408889634f)   // -K*log2(e)
#define FIXP     512.0f
#define INV_FIXP (1.0f / 512.0f)
#define CNT_ONE  (1u << 20)
#define SI_MASK  0xFFFFFu

__global__ __launch_bounds__(THREADS) void ect_kernel(
    const float* __restrict__ x,      // [N,3]
    const float* __restrict__ dirs,   // [3,T]
    const int*   __restrict__ batch,  // [N] sorted, values in [0,64)
    float* __restrict__ out,          // [B,R,T]
    int N)
{
    __shared__ unsigned s_a[NROWS * TQW];       // 1040 B packed bins
    __shared__ int      s_lo, s_hi;

    const int tid  = threadIdx.x;
    const int b    = blockIdx.x >> 4;
    const int q    = blockIdx.x & (TSPLIT - 1);
    const int lane = tid & 63;
    const int w    = tid >> 6;

    for (int i = tid; i < NROWS * TQW; i += THREADS) s_a[i] = 0u;
    if (tid == 0) {
        s_lo = (b == 0) ? 0 : -1;               // analytic: batch[j] >= 0
        s_hi = (b == N_BATCH - 1) ? N : -1;     // analytic: batch[j] <= 63
    }

    // 12 block-uniform dir components -> scalar regs
    float D0[TQW], D1[TQW], D2[TQW];
#pragma unroll
    for (int j = 0; j < TQW; ++j) {
        D0[j] = dirs[q * TQW + j];
        D1[j] = dirs[T_DIRS + q * TQW + j];
        D2[j] = dirs[2 * T_DIRS + q * TQW + j];
    }
    __syncthreads();

    // single-exposure boundary scan: 4 candidates per window per thread.
    {
        const int seg = N >> 6;                 // 1024
        const int clo = b * seg;
        const int chi = (b + 1) * seg;
        const bool doLo = (b != 0);
        const bool doHi = (b != N_BATCH - 1);   // uniform branches
        const int lob = clo - 1024 + 4 * tid;   // 16B-aligned
        const int hib = chi - 1024 + 4 * tid;
        int4 elo, ehi;
        int  plo = -1, phi = -1;
        if (doLo) {
            elo = *(const int4*)&batch[lob];
            plo = (lob == 0) ? -1 : batch[lob - 1];
        }
        if (doHi) {
            ehi = *(const int4*)&batch[hib];
            phi = (hib == 0) ? -1 : batch[hib - 1];
        }
        if (doLo) {
            int v[5] = {plo, elo.x, elo.y, elo.z, elo.w};
#pragma unroll
            for (int i = 0; i < 4; ++i)
                if (v[i + 1] >= b && v[i] < b) s_lo = lob + i;
        }
        if (doHi) {
            int v[5] = {phi, ehi.x, ehi.y, ehi.z, ehi.w};
#pragma unroll
            for (int i = 0; i < 4; ++i)
                if (v[i + 1] > b && v[i] <= b) s_hi = hib + i;
        }
    }
    __syncthreads();

    // fallback: full coalesced sweep iff a sentinel survived (prob ~1e-15)
    if (s_lo < 0 || s_hi < 0) {
        for (int j = tid; j < N; j += THREADS) {
            int v  = batch[j];
            int vp = (j == 0) ? -1 : batch[j - 1];
            if (v >= b && vp < b)  s_lo = j;
            if (v >  b && vp <= b) s_hi = j;
        }
        __syncthreads();
    }
    const int lo  = (s_lo < 0) ? N : s_lo;
    const int hi  = (s_hi < 0) ? N : s_hi;
    const int len = hi - lo;
    const float* xb = x + (size_t)lo * 3;

    // inner loop: lane = point; 64 consecutive points/wave-iter (coalesced);
    // 4 dirs per lane in registers; ~2 serial iterations for len~1024.
    for (int p0 = w * 64; p0 < len; p0 += NWAVES * 64) {
        int p = p0 + lane;
        if (p < len) {
            float x0 = xb[p * 3 + 0];
            float x1 = xb[p * 3 + 1];
            float x2 = xb[p * 3 + 2];
#pragma unroll
            for (int j = 0; j < TQW; ++j) {
                float nh  = fmaf(x2, D2[j], fmaf(x1, D1[j], x0 * D0[j]));
                float u   = fmaf(nh, INV_STEP, OFF_F);
                float r0f = rintf(u);
                float dd  = r0f - u;                           // [-0.5, 0.5]
                float e   = __builtin_amdgcn_exp2f(dd * MEXP);
                float s   = __builtin_amdgcn_rcpf(1.0f + e);   // sigmoid at r0
                unsigned si = (unsigned)fmaf(s, FIXP, 0.5f);   // [0, 2^9]
                int j1 = (int)r0f + 1;
                if (j1 <= R_STEPS) {            // skip upper-tail trash
                    j1 = max(j1, 0);
                    atomicAdd(&s_a[j1 * TQW + j], CNT_ONE | si);
                }
            }
        }
    }
    __syncthreads();
    if (w != 0) return;                         // single-wave epilogue

    // lane r handles output row r for the block's 4 dirs.
    uint4 rowv = *(const uint4*)&s_a[lane * TQW];          // ds_read_b128
    uint4 r64  = *(const uint4*)&s_a[R_STEPS * TQW];       // row 64 broadcast

    unsigned c0 = rowv.x >> 20, c1 = rowv.y >> 20,
             c2 = rowv.z >> 20, c3 = rowv.w >> 20;
    unsigned s0 = rowv.x & SI_MASK, s1 = rowv.y & SI_MASK,
             s2 = rowv.z & SI_MASK, s3 = rowv.w & SI_MASK;

    unsigned n0 = __shfl_down(s0, 1, 64), n1 = __shfl_down(s1, 1, 64),
             n2 = __shfl_down(s2, 1, 64), n3 = __shfl_down(s3, 1, 64);
    if (lane == 63) {
        n0 = r64.x & SI_MASK; n1 = r64.y & SI_MASK;
        n2 = r64.z & SI_MASK; n3 = r64.w & SI_MASK;
    }

#pragma unroll
    for (int d = 1; d < 64; d <<= 1) {
        unsigned u0 = __shfl_up(c0, d, 64), u1 = __shfl_up(c1, d, 64),
                 u2 = __shfl_up(c2, d, 64), u3 = __shfl_up(c3, d, 64);
        if (lane >= d) { c0 += u0; c1 += u1; c2 += u2; c3 += u3; }
    }

    float4 o;
    o.x = (float)c0 + (float)n0 * INV_FIXP;
    o.y = (float)c1 + (float)n1 * INV_FIXP;
    o.z = (float)c2 + (float)n2 * INV_FIXP;
    o.w = (float)c3 + (float)n3 * INV_FIXP;
    *(float4*)&out[((size_t)b << 12) | (lane << 6) | (q * TQW)] = o;
}

extern "C" void kernel_launch(void* const* d_in, const int* in_sizes, int n_in,
                              void* d_out, int out_size, void* d_ws, size_t ws_size,
                              hipStream_t stream) {
    const float* x     = (const float*)d_in[0];
    const float* dirs  = (const float*)d_in[1];
    const int*   batch = (const int*)d_in[3];
    float* out = (float*)d_out;
    const int N = in_sizes[3];

    ect_kernel<<<dim3(N_BATCH * TSPLIT), dim3(THREADS), 0, stream>>>(
        x, dirs, batch, out, N);
}